// Round 2
// baseline (431.701 us; speedup 1.0000x reference)
//
#include <hip/hip_runtime.h>

#define Bc 8
#define Tc 4096
#define Dc 768
#define Hc 12
#define HDc 64
#define Kc 32
#define TD3 2304

typedef __attribute__((ext_vector_type(8))) short short8;
typedef __attribute__((ext_vector_type(4))) float float4v;

__device__ __forceinline__ float bf2f(unsigned short u) {
    unsigned v = ((unsigned)u) << 16;
    return __builtin_bit_cast(float, v);
}
__device__ __forceinline__ unsigned short f2bf(float f) {
    unsigned u = __builtin_bit_cast(unsigned, f);
    u += 0x7FFFu + ((u >> 16) & 1u);   // RNE
    return (unsigned short)(u >> 16);
}

// split fp32x8 into bf16 hi + bf16 lo fragments (hi+lo ~ fp32 precision)
__device__ __forceinline__ void split8(const float* p, short8& hi, short8& lo) {
    float4v a0 = *(const float4v*)p;
    float4v a1 = *(const float4v*)(p + 4);
#pragma unroll
    for (int i = 0; i < 4; ++i) {
        unsigned short h = f2bf(a0[i]);
        hi[i] = (short)h;
        lo[i] = (short)f2bf(a0[i] - bf2f(h));
        unsigned short h2 = f2bf(a1[i]);
        hi[i + 4] = (short)h2;
        lo[i + 4] = (short)f2bf(a1[i] - bf2f(h2));
    }
}
__device__ __forceinline__ void split8v(float4v a0, float4v a1, short8& hi, short8& lo) {
#pragma unroll
    for (int i = 0; i < 4; ++i) {
        unsigned short h = f2bf(a0[i]);
        hi[i] = (short)h;
        lo[i] = (short)f2bf(a0[i] - bf2f(h));
        unsigned short h2 = f2bf(a1[i]);
        hi[i + 4] = (short)h2;
        lo[i + 4] = (short)f2bf(a1[i] - bf2f(h2));
    }
}

// K1: x_spec[b,k,d] = sum_t sb[b,t,k] * x[b,t,d]  (atomic over 16 T-chunks)
__global__ __launch_bounds__(256) void k1_xspec(const float* __restrict__ x,
                                                const float* __restrict__ sb,
                                                float* __restrict__ xs) {
    __shared__ float sbl[256 * 32];
    int tid = threadIdx.x;
    int bid = blockIdx.x;                 // 8 * 3 * 16 = 384 blocks
    int b = bid / 48;
    int rem = bid % 48;
    int dt = rem / 16;
    int tc = rem % 16;
    int d  = dt * 256 + tid;
    int t0 = tc * 256;

    const float* sbp = sb + ((size_t)(b * Tc + t0)) * Kc;
    for (int i = tid; i < 256 * 32; i += 256) sbl[i] = sbp[i];
    __syncthreads();

    float acc[Kc];
#pragma unroll
    for (int k = 0; k < Kc; ++k) acc[k] = 0.f;

    const float* xp = x + ((size_t)(b * Tc + t0)) * Dc + d;
    for (int tt = 0; tt < 256; ++tt) {
        float xv = xp[(size_t)tt * Dc];
        const float* srow = &sbl[tt * Kc];
#pragma unroll
        for (int k = 0; k < Kc; ++k) acc[k] = fmaf(xv, srow[k], acc[k]);
    }

    float* xsp = xs + (size_t)b * Kc * Dc + d;
#pragma unroll
    for (int k = 0; k < Kc; ++k) atomicAdd(xsp + (size_t)k * Dc, acc[k]);
}

// K2: c1[r, j] = sum_c xs[r, c] * wqkv[j, c];  r in [0,256), j in [0,2304)
// wave computes 64 rows x 32 cols via 4 m-tiles x 2 n-accumulators, hi/lo split
__global__ __launch_bounds__(256) void k2_qkv(const float* __restrict__ xs,
                                              const float* __restrict__ wqkv,
                                              float* __restrict__ c1) {
    int wave = blockIdx.x * 4 + (threadIdx.x >> 6);   // 72 blocks -> 288 waves
    int lane = threadIdx.x & 63;
    int mb = wave & 3;          // 4 m-blocks (64 rows)
    int nt = wave >> 2;         // 72 n-tiles (32 cols)
    int m0 = mb * 64, n0 = nt * 32;
    int m = lane & 15, quad = lane >> 4;

    const float* ap  = xs   + (size_t)(m0 + m) * Dc + quad * 8;
    const float* bp0 = wqkv + (size_t)(n0 + m) * Dc + quad * 8;
    const float* bp1 = bp0 + (size_t)16 * Dc;

    float4v acc[4][2];
#pragma unroll
    for (int i = 0; i < 4; ++i)
#pragma unroll
        for (int j = 0; j < 2; ++j) acc[i][j] = (float4v){0.f, 0.f, 0.f, 0.f};

    for (int s = 0; s < 24; ++s) {
        short8 bh0, bl0, bh1, bl1;
        split8(bp0 + s * 32, bh0, bl0);
        split8(bp1 + s * 32, bh1, bl1);
#pragma unroll
        for (int mt = 0; mt < 4; ++mt) {
            short8 ah, al;
            split8(ap + (size_t)mt * 16 * Dc + s * 32, ah, al);
            acc[mt][0] = __builtin_amdgcn_mfma_f32_16x16x32_bf16(ah, bh0, acc[mt][0], 0, 0, 0);
            acc[mt][0] = __builtin_amdgcn_mfma_f32_16x16x32_bf16(al, bh0, acc[mt][0], 0, 0, 0);
            acc[mt][0] = __builtin_amdgcn_mfma_f32_16x16x32_bf16(ah, bl0, acc[mt][0], 0, 0, 0);
            acc[mt][1] = __builtin_amdgcn_mfma_f32_16x16x32_bf16(ah, bh1, acc[mt][1], 0, 0, 0);
            acc[mt][1] = __builtin_amdgcn_mfma_f32_16x16x32_bf16(al, bh1, acc[mt][1], 0, 0, 0);
            acc[mt][1] = __builtin_amdgcn_mfma_f32_16x16x32_bf16(ah, bl1, acc[mt][1], 0, 0, 0);
        }
    }
    int col = lane & 15;
#pragma unroll
    for (int mt = 0; mt < 4; ++mt) {
        float* cp = c1 + (size_t)(m0 + mt * 16 + quad * 4) * TD3 + n0 + col;
#pragma unroll
        for (int r = 0; r < 4; ++r) {
            cp[(size_t)r * TD3]      = acc[mt][0][r];
            cp[(size_t)r * TD3 + 16] = acc[mt][1][r];
        }
    }
}

// K3: attn dot (q.k)/8 * sigmoid(filter) -> FHN -> fhn[b,h,k]
__global__ __launch_bounds__(256) void k3_fhn(const float* __restrict__ c1,
                                              const float* __restrict__ sfilt,
                                              float* __restrict__ fhn) {
    int idx = blockIdx.x * 256 + threadIdx.x;   // 12 blocks -> 3072
    if (idx >= Bc * Hc * Kc) return;
    int kk = idx & 31;
    int bh = idx >> 5;
    int h  = bh % Hc;
    int r  = (bh / Hc) * Kc + kk;

    const float* qp = c1 + (size_t)r * TD3 + h * HDc;
    const float* kp = qp + Dc;
    float s = 0.f;
#pragma unroll
    for (int dd = 0; dd < HDc; ++dd) s = fmaf(qp[dd], kp[dd], s);
    s *= 0.125f;

    float filt = 1.f / (1.f + __expf(-sfilt[h * 32 + kk]));
    s *= filt;

    float as    = fabsf(s);
    float scale = fmaxf(as, 1e-6f);
    float sn    = s / scale;
    float gate  = 1.f / (1.f + __expf(-(as - 0.5f) * 10.f));
    float I     = sn * (0.1f + 0.9f * gate);
    const float alpha = 0.08f;    // DT/TAU
    const float denom = 1.064f;   // 1 + alpha*B
    float v = 0.f, w = 0.f;
#pragma unroll
    for (int it = 0; it < 2; ++it) {
        float dv = v - (v * v * v) / 3.f - w + I;
        float vn = v + dv;
        float wn = (w + (vn + 0.7f) * alpha) / denom;
        v = fminf(fmaxf(vn, -3.f), 3.f);
        w = fminf(fmaxf(wn, -3.f), 3.f);
    }
    fhn[idx] = v * scale;
}

// K4: proj[r,e] = sum_c (fhn[b,h(c),kk(r)] * v_spec[r,c]) * wout[e,c]
__global__ __launch_bounds__(256) void k4_proj(const float* __restrict__ c1,
                                               const float* __restrict__ fhn,
                                               const float* __restrict__ wout,
                                               float* __restrict__ proj) {
    int wave = blockIdx.x * 4 + (threadIdx.x >> 6);   // 48 blocks -> 192 waves
    int lane = threadIdx.x & 63;
    int mb = wave & 3;     // 4 m-blocks (64 rows)
    int nt = wave >> 2;    // 48 n-tiles (16 cols)
    int m0 = mb * 64, n0 = nt * 16;
    int m = lane & 15, quad = lane >> 4;

    const float* bp = wout + (size_t)(n0 + m) * Dc + quad * 8;

    float4v acc[4];
#pragma unroll
    for (int i = 0; i < 4; ++i) acc[i] = (float4v){0.f, 0.f, 0.f, 0.f};

    for (int s = 0; s < 24; ++s) {
        short8 bh, bl;
        split8(bp + s * 32, bh, bl);
        int c0 = s * 32 + quad * 8;
        int h  = c0 >> 6;
#pragma unroll
        for (int mt = 0; mt < 4; ++mt) {
            int r = m0 + mt * 16 + m;
            int b = r >> 5, kk = r & 31;
            float f = fhn[(size_t)b * Hc * Kc + h * Kc + kk];
            const float* apx = c1 + (size_t)r * TD3 + 2 * Dc + s * 32 + quad * 8;
            float4v a0 = *(const float4v*)apx;
            float4v a1 = *(const float4v*)(apx + 4);
#pragma unroll
            for (int i = 0; i < 4; ++i) { a0[i] *= f; a1[i] *= f; }
            short8 ah, al;
            split8v(a0, a1, ah, al);
            acc[mt] = __builtin_amdgcn_mfma_f32_16x16x32_bf16(ah, bh, acc[mt], 0, 0, 0);
            acc[mt] = __builtin_amdgcn_mfma_f32_16x16x32_bf16(al, bh, acc[mt], 0, 0, 0);
            acc[mt] = __builtin_amdgcn_mfma_f32_16x16x32_bf16(ah, bl, acc[mt], 0, 0, 0);
        }
    }
#pragma unroll
    for (int mt = 0; mt < 4; ++mt) {
        float* cp = proj + (size_t)(m0 + mt * 16 + quad * 4) * Dc + n0 + (lane & 15);
#pragma unroll
        for (int r = 0; r < 4; ++r) cp[(size_t)r * Dc] = acc[mt][r];
    }
}

// K5: out[b,t,e] = sum_k sb[b,t,k] * proj[b,k,e]
__global__ __launch_bounds__(256) void k5_out(const float* __restrict__ proj,
                                              const float* __restrict__ sb,
                                              float* __restrict__ out) {
    __shared__ float sbl[256 * 32];
    int tid = threadIdx.x;
    int bid = blockIdx.x;                 // 384 blocks
    int b = bid / 48;
    int rem = bid % 48;
    int dt = rem / 16;
    int tc = rem % 16;
    int d  = dt * 256 + tid;
    int t0 = tc * 256;

    const float* sbp = sb + ((size_t)(b * Tc + t0)) * Kc;
    for (int i = tid; i < 256 * 32; i += 256) sbl[i] = sbp[i];
    __syncthreads();

    float p[Kc];
    const float* pp = proj + (size_t)b * Kc * Dc + d;
#pragma unroll
    for (int k = 0; k < Kc; ++k) p[k] = pp[(size_t)k * Dc];

    float* op = out + ((size_t)(b * Tc + t0)) * Dc + d;
    for (int tt = 0; tt < 256; ++tt) {
        float a = 0.f;
        const float* srow = &sbl[tt * Kc];
#pragma unroll
        for (int k = 0; k < Kc; ++k) a = fmaf(srow[k], p[k], a);
        op[(size_t)tt * Dc] = a;
    }
}

extern "C" void kernel_launch(void* const* d_in, const int* in_sizes, int n_in,
                              void* d_out, int out_size, void* d_ws, size_t ws_size,
                              hipStream_t stream) {
    const float* x     = (const float*)d_in[0];
    const float* sb    = (const float*)d_in[1];
    const float* wqkv  = (const float*)d_in[2];
    const float* wout  = (const float*)d_in[3];
    const float* sfilt = (const float*)d_in[4];
    float* out = (float*)d_out;

    float* xs   = (float*)d_ws;                 // [B][K][D]   196608 f
    float* c1   = xs + (size_t)Bc * Kc * Dc;    // [256][2304] 589824 f
    float* fhn  = c1 + (size_t)Bc * Kc * TD3;   // [B][H][K]     3072 f
    float* proj = fhn + (size_t)Bc * Hc * Kc;   // [256][768]  196608 f

    hipMemsetAsync(xs, 0, (size_t)Bc * Kc * Dc * sizeof(float), stream);
    hipLaunchKernelGGL(k1_xspec, dim3(384), dim3(256), 0, stream, x, sb, xs);
    hipLaunchKernelGGL(k2_qkv,   dim3(72),  dim3(256), 0, stream, xs, wqkv, c1);
    hipLaunchKernelGGL(k3_fhn,   dim3(12),  dim3(256), 0, stream, c1, sfilt, fhn);
    hipLaunchKernelGGL(k4_proj,  dim3(48),  dim3(256), 0, stream, c1, fhn, wout, proj);
    hipLaunchKernelGGL(k5_out,   dim3(384), dim3(256), 0, stream, proj, sb, out);
}